// Round 1
// baseline (261.071 us; speedup 1.0000x reference)
//
#include <hip/hip_runtime.h>
#include <hip/hip_bf16.h>
#include <stdint.h>

// Problem constants: B=4, T=2048, C=1024, H=16, D=64. Inputs f32, output f32.
#define B_ 4
#define T_ 2048
#define C_ 1024
#define H_ 16
#define D_ 64

typedef __bf16 bf16;
typedef _Float16 f16;
typedef __attribute__((ext_vector_type(8))) __bf16 bf16x8;
typedef __attribute__((ext_vector_type(4))) __bf16 bf16x4;
typedef __attribute__((ext_vector_type(4))) _Float16 f16x4;
typedef __attribute__((ext_vector_type(8))) _Float16 f16x8;
typedef __attribute__((ext_vector_type(4))) float floatx4;

__device__ __forceinline__ floatx4 mfma16(bf16x8 a, bf16x8 b, floatx4 c) {
  return __builtin_amdgcn_mfma_f32_16x16x32_bf16(a, b, c, 0, 0, 0);
}
__device__ __forceinline__ floatx4 mfma_pv(f16x4 a, f16x4 b, floatx4 c) {
  return __builtin_amdgcn_mfma_f32_16x16x16f16(a, b, c, 0, 0, 0);
}

__device__ __forceinline__ void gl_lds16(const void* g, void* l) {
  __builtin_amdgcn_global_load_lds(
      (__attribute__((address_space(1))) uint32_t*)g,
      (__attribute__((address_space(3))) uint32_t*)l, 16, 0, 0);
}

// ---------------- f32 -> bf16 bulk convert ----------------
__global__ __launch_bounds__(256) void cvt_bf16(const float* __restrict__ in,
                                                bf16* __restrict__ out) {
  const size_t i = ((size_t)blockIdx.x * 256 + threadIdx.x) * 4;
  const floatx4 v = *(const floatx4*)(in + i);
  bf16x4 r;
#pragma unroll
  for (int j = 0; j < 4; j++) r[j] = (bf16)v[j];
  *(bf16x4*)(out + i) = r;
}

// ---------------- transpose: in[K][N] f32 -> out[N][K] bf16 ----------------
__global__ __launch_bounds__(256) void transpose_f32(const float* __restrict__ in,
                                                     bf16* __restrict__ out,
                                                     int K, int N) {
  __shared__ bf16 tile[32][33];
  const int n0 = blockIdx.x * 32, k0 = blockIdx.y * 32;
  const int r = threadIdx.x >> 5, c = threadIdx.x & 31;
#pragma unroll
  for (int i = 0; i < 4; i++)
    tile[r + i * 8][c] = (bf16)in[(size_t)(k0 + r + i * 8) * N + n0 + c];
  __syncthreads();
#pragma unroll
  for (int i = 0; i < 4; i++)
    out[(size_t)(n0 + r + i * 8) * K + k0 + c] = tile[c][r + i * 8];
}

// ============================================================================
// QKV GEMM, 8-phase 256x256 template (T2 swizzle + T4 counted vmcnt + T5).
// C[M=3072, N=8192] = A[M,K=1024] @ Bt[N,K]^T, SWAPPED orientation:
//   A = wqkv_t (rows = channels), Bt = xb (rows = tokens).
// Geometry: BM=BN=256, BK=32, 512 thr = 8 waves (2M x 4N), per-wave 128x64
//   => acc[8][4] floatx4.  NBUF=4 K-tile LDS buffers (4 x 32 KiB = 128 KiB
//   dynamic LDS, 1 block/CU).  Per K-tile: 2 phases x 16 MFMA.
// Staging: phase 0 of tile t stages A-halves of tile t+3, phase 1 its
//   B-halves (2 x global_load_lds each).  One vmcnt(8) per K-tile => tile
//   t+1 fully landed, 8 loads (2 tiles) stay in flight.  Tail: 8 -> 4 -> 0.
// Swizzle: LDS row = 64 B = 4 x 16B chunks; chunk ^= (row>>1)&3, applied to
//   the GLOBAL source (LDS dest linear for global_load_lds) and to ds_read
//   addr => quarter-wave spans all 32 banks (2-way residual = free).
// ============================================================================
__global__ __launch_bounds__(512, 2) void gemm_qkv(const bf16* __restrict__ A,
                                                   const bf16* __restrict__ Bt,
                                                   const float* __restrict__ bias,
                                                   bf16* __restrict__ Qb,
                                                   bf16* __restrict__ Kp,
                                                   f16* __restrict__ Vp) {
  extern __shared__ __align__(16) char smem_[];
  const int tid = threadIdx.x;
  const int lane = tid & 63, wv = tid >> 6;  // 8 waves
  const int col = lane & 15, quad = lane >> 4;
  const int wm = wv >> 2, wn = wv & 3;  // 2M x 4N

  // XCD-aware swizzle (384 % 8 == 0 -> simple chunked form is bijective).
  // B-panel-major: each XCD's 48 blocks share 4 token panels (2 MB, L2-fit).
  const int id0 = blockIdx.x;
  const int sw = (id0 & 7) * 48 + (id0 >> 3);
  const int bx = sw / 12, by = sw - bx * 12;
  const int m0 = by * 256, n0 = bx * 256;  // m0: channels, n0: tokens

  // ---- staging addresses (per thread; source pre-swizzled) ----
  const int srow = tid >> 2;   // row within 128-row half
  const int schunk = tid & 3;  // 16B chunk within 64B row
  const int sx = ((schunk ^ ((srow >> 1) & 3)) << 3);  // element offset
  const bf16* baseA0 = A + (size_t)(m0 + srow) * 1024 + sx;
  const bf16* baseA1 = baseA0 + (size_t)128 * 1024;
  const bf16* baseB0 = Bt + (size_t)(n0 + srow) * 1024 + sx;
  const bf16* baseB1 = baseB0 + (size_t)128 * 1024;
  const int wvo = wv << 10;  // wave's linear 1 KiB LDS slice per half-tile

  // ---- fragment-read offsets (swizzled) ----
  // key (row>>1)&3 == (col>>1)&3 for all frag rows (wm*128, wn*64, *16 ≡ 0 mod 8)
  const int fswz = col * 64 + ((quad ^ ((col >> 1) & 3)) << 4);
  const int aoff = (wm << 13) + fswz;           // A region: rows wm*128+..
  const int boff = 16384 + (wn << 12) + fswz;   // B region: rows wn*64+..

  floatx4 acc[8][4];
#pragma unroll
  for (int i = 0; i < 8; ++i)
#pragma unroll
    for (int j = 0; j < 4; ++j) acc[i][j] = (floatx4){0.f, 0.f, 0.f, 0.f};

  // ---- prologue: stage K-tiles 0..2 (12 loads), land tile 0 ----
#pragma unroll
  for (int pt = 0; pt < 3; ++pt) {
    char* sb = smem_ + (pt << 15) + wvo;
    gl_lds16(baseA0 + pt * 32, sb);
    gl_lds16(baseA1 + pt * 32, sb + 8192);
    gl_lds16(baseB0 + pt * 32, sb + 16384);
    gl_lds16(baseB1 + pt * 32, sb + 24576);
  }
  asm volatile("s_waitcnt vmcnt(8)" ::: "memory");
  __builtin_amdgcn_s_barrier();

  for (int t = 0; t < 32; ++t) {
    const char* bufp = smem_ + ((t & 3) << 15);
    const int st = t + 3;
    char* sb = smem_ + ((st & 3) << 15) + wvo;
    // ---------------- phase 0: A mb0-3 + all B, stage A(t+3) --------------
    bf16x8 afr[4], bfr[4];
#pragma unroll
    for (int mb = 0; mb < 4; ++mb)
      afr[mb] = *(const bf16x8*)(bufp + aoff + mb * 1024);
#pragma unroll
    for (int nb = 0; nb < 4; ++nb)
      bfr[nb] = *(const bf16x8*)(bufp + boff + nb * 1024);
    if (st < 32) {
      gl_lds16(baseA0 + st * 32, sb);
      gl_lds16(baseA1 + st * 32, sb + 8192);
    }
    __builtin_amdgcn_s_barrier();
    __builtin_amdgcn_sched_barrier(0);
    __builtin_amdgcn_s_setprio(1);
#pragma unroll
    for (int mb = 0; mb < 4; ++mb)
#pragma unroll
      for (int nb = 0; nb < 4; ++nb)
        acc[mb][nb] = mfma16(afr[mb], bfr[nb], acc[mb][nb]);
    __builtin_amdgcn_s_setprio(0);
    __builtin_amdgcn_sched_barrier(0);
    __builtin_amdgcn_s_barrier();
    // ---------------- phase 1: A mb4-7 (B held in regs), stage B(t+3) -----
    bf16x8 afr2[4];
#pragma unroll
    for (int mb = 0; mb < 4; ++mb)
      afr2[mb] = *(const bf16x8*)(bufp + aoff + (mb + 4) * 1024);
    if (st < 32) {
      gl_lds16(baseB0 + st * 32, sb + 16384);
      gl_lds16(baseB1 + st * 32, sb + 24576);
    }
    __builtin_amdgcn_s_barrier();
    __builtin_amdgcn_sched_barrier(0);
    __builtin_amdgcn_s_setprio(1);
#pragma unroll
    for (int mb = 0; mb < 4; ++mb)
#pragma unroll
      for (int nb = 0; nb < 4; ++nb)
        acc[mb + 4][nb] = mfma16(afr2[mb], bfr[nb], acc[mb + 4][nb]);
    __builtin_amdgcn_s_setprio(0);
    __builtin_amdgcn_sched_barrier(0);
    // tile-boundary counted wait: tile t+1 landed, 2 tiles stay in flight
    if (t < 29)
      asm volatile("s_waitcnt vmcnt(8)" ::: "memory");
    else if (t == 29)
      asm volatile("s_waitcnt vmcnt(4)" ::: "memory");
    else if (t == 30)
      asm volatile("s_waitcnt vmcnt(0)" ::: "memory");
    __builtin_amdgcn_s_barrier();
  }

  // ---- epilogue: third is block-uniform (256 | 1024) ----
  const int third = by >> 2;
  const int wrow = wm * 128, wcol = wn * 64;
#pragma unroll
  for (int mb = 0; mb < 8; ++mb) {
    const int mgq = m0 + wrow + mb * 16 + quad * 4;  // 4 consecutive channels
    const int nn0 = mgq & 1023;
    const int h = nn0 >> 6, d0 = nn0 & 63;  // d0 4-aligned
    float bs[4];
#pragma unroll
    for (int r = 0; r < 4; ++r) bs[r] = bias[mgq + r];
#pragma unroll
    for (int nb = 0; nb < 4; ++nb) {
      const int tk = n0 + wcol + nb * 16 + col;  // token
      const int bb = tk >> 11, tt = tk & 2047;
      const size_t bh = (size_t)bb * H_ + h;
      float v[4];
#pragma unroll
      for (int r = 0; r < 4; ++r) v[r] = acc[mb][nb][r] + bs[r];
      if (third == 0) {
        bf16x4 y;
#pragma unroll
        for (int r = 0; r < 4; ++r) y[r] = (bf16)v[r];
        *(bf16x4*)&Qb[(bh * T_ + tt) * D_ + d0] = y;
      } else if (third == 1) {
        const int lane2 = (tt & 15) | (((d0 >> 3) & 3) << 4);
        const size_t idx =
            ((((bh * 64 + (tt >> 5)) * 2 + ((tt >> 4) & 1)) * 2 + (d0 >> 5)) * 64 +
             lane2) * 8 + (d0 & 7);
        bf16x4 y;
#pragma unroll
        for (int r = 0; r < 4; ++r) y[r] = (bf16)v[r];
        *(bf16x4*)&Kp[idx] = y;
      } else {
#pragma unroll
        for (int r = 0; r < 4; ++r) {
          const int d = d0 + r;
          const int lane2 = (d & 15) | (((tt >> 2) & 3) << 4);
          const size_t idx =
              (((bh * 64 + (tt >> 5)) * 4 + (d >> 4)) * 64 + lane2) * 8 +
              ((tt >> 4) & 1) * 4 + (tt & 3);
          Vp[idx] = (f16)v[r];
        }
      }
    }
  }
}

// ---------------- 128x128 bf16 MFMA GEMM, BK=64 (proj only now) ------------
// MODE 1 (proj): A=yb rows=tokens, bias by column, f32 row-major out.
template <int MODE>
__global__ __launch_bounds__(256) void gemm128(const bf16* __restrict__ A,
                                               const bf16* __restrict__ Bt,
                                               const float* __restrict__ bias,
                                               void* __restrict__ o0,
                                               bf16* __restrict__ o1,
                                               f16* __restrict__ o2,
                                               int M, int N, int K) {
  __shared__ __align__(16) bf16 As[2][128 * 32];
  __shared__ __align__(16) bf16 Bs[2][128 * 32];
  const int tid = threadIdx.x;
  const int m0 = blockIdx.y * 128, n0 = blockIdx.x * 128;
  const int lane = tid & 63, wv = tid >> 6;
  const int wm = (wv >> 1) * 64, wn = (wv & 1) * 64;
  const int col = lane & 15, quad = lane >> 4;

  floatx4 acc[4][4];
#pragma unroll
  for (int i = 0; i < 4; i++)
#pragma unroll
    for (int j = 0; j < 4; j++) acc[i][j] = (floatx4){0.f, 0.f, 0.f, 0.f};

  const int c0 = tid, c1 = tid + 256;
  const bf16* a0 = A + (size_t)(m0 + (c0 >> 2)) * K + (c0 & 3) * 8;
  const bf16* a1 = A + (size_t)(m0 + (c1 >> 2)) * K + (c1 & 3) * 8;
  const bf16* b0 = Bt + (size_t)(n0 + (c0 >> 2)) * K + (c0 & 3) * 8;
  const bf16* b1 = Bt + (size_t)(n0 + (c1 >> 2)) * K + (c1 & 3) * 8;

  for (int kt = 0; kt < K; kt += 64) {
#pragma unroll
    for (int hf = 0; hf < 2; hf++) {
      const int ko = kt + hf * 32;
      gl_lds16(a0 + ko, &As[hf][(wv * 64) * 8]);
      gl_lds16(a1 + ko, &As[hf][(wv * 64 + 256) * 8]);
      gl_lds16(b0 + ko, &Bs[hf][(wv * 64) * 8]);
      gl_lds16(b1 + ko, &Bs[hf][(wv * 64 + 256) * 8]);
    }
    __syncthreads();
#pragma unroll
    for (int hf = 0; hf < 2; hf++) {
      bf16x8 afr[4], bg[4];
#pragma unroll
      for (int mb = 0; mb < 4; mb++)
        afr[mb] = *(const bf16x8*)&As[hf][(wm + mb * 16 + col) * 32 + quad * 8];
#pragma unroll
      for (int nb = 0; nb < 4; nb++)
        bg[nb] = *(const bf16x8*)&Bs[hf][(wn + nb * 16 + col) * 32 + quad * 8];
#pragma unroll
      for (int mb = 0; mb < 4; mb++)
#pragma unroll
        for (int nb = 0; nb < 4; nb++)
          acc[mb][nb] = mfma16(afr[mb], bg[nb], acc[mb][nb]);
    }
    __syncthreads();
  }

#pragma unroll
  for (int mb = 0; mb < 4; mb++) {
    const int mgq = m0 + wm + mb * 16 + quad * 4;  // 4 consecutive rows
    {
#pragma unroll
      for (int nb = 0; nb < 4; nb++) {
        const int ng = n0 + wn + nb * 16 + col;
        const float bsc = bias[ng];
#pragma unroll
        for (int r = 0; r < 4; r++)
          ((float*)o0)[(size_t)(mgq + r) * N + ng] = acc[mb][nb][r] + bsc;
      }
    }
  }
}

// ---------------- flash attention: block = (bh, qtile); 4-way key split ----
// Q: [B,H,T,D] bf16; Kp/Vp: fragment-major (see gemm_qkv); Y: [B,T,C] bf16
__global__ __launch_bounds__(256, 4) void attn(const bf16* __restrict__ Q,
                                               const bf16* __restrict__ Kp,
                                               const f16* __restrict__ Vp,
                                               bf16* __restrict__ Y) {
  const int tid = threadIdx.x, lane = tid & 63, wv = tid >> 6;
  const int col = lane & 15, quad = lane >> 4;
  const int id = blockIdx.x;
  const int j = id >> 3;
  const int bh = ((j & 7) << 3) | (id & 7);
  const int qtile = 63 - (j >> 3);  // longest blocks dispatch first
  const int b = bh >> 4, h = bh & 15;
  const int qbase = qtile * 32;

  __shared__ __align__(16) floatx4 mbuf[3][8][64];  // 24 KB partial-O
  __shared__ float lbuf[3][2][64];                  // 1.5 KB partial-lsum

  bf16x8 qf[2][2];
#pragma unroll
  for (int mq = 0; mq < 2; mq++) {
    const bf16* qp = Q + ((size_t)bh * T_ + qbase + mq * 16 + col) * D_ + quad * 8;
    qf[mq][0] = *(const bf16x8*)qp;
    qf[mq][1] = *(const bf16x8*)(qp + 32);
  }

  floatx4 o[2][4];  // O^T: dim = sub*16 + quad*4 + r, qrow = col
  float lsum[2] = {0.f, 0.f};
#pragma unroll
  for (int mq = 0; mq < 2; mq++)
#pragma unroll
    for (int s = 0; s < 4; s++) o[mq][s] = (floatx4){0.f, 0.f, 0.f, 0.f};

  const float C1 = 0.18033688f;  // 0.125*log2(e)
  const float C2 = 11.541560f;   // 8*log2(e): p = exp2(s*C1 - C2), exact softmax

  const int nmine = (qtile >= wv) ? ((qtile - wv) >> 2) + 1 : 0;

  for (int i = 0; i < nmine; i++) {
    const int kt = wv + 4 * i;
    const bool masked = (kt == qtile);
    const bf16* kbase = Kp + ((size_t)bh * 64 + kt) * 2048 + lane * 8;
    const f16* vbase = Vp + ((size_t)bh * 64 + kt) * 2048 + lane * 8;
    bf16x8 ka[2][2];
    ka[0][0] = *(const bf16x8*)(kbase);
    ka[0][1] = *(const bf16x8*)(kbase + 512);
    ka[1][0] = *(const bf16x8*)(kbase + 1024);
    ka[1][1] = *(const bf16x8*)(kbase + 1536);
    f16x8 vv[4];
#pragma unroll
    for (int sub = 0; sub < 4; sub++) vv[sub] = *(const f16x8*)(vbase + sub * 512);

#pragma unroll
    for (int st = 0; st < 2; st++) {
#pragma unroll
      for (int mq = 0; mq < 2; mq++) {
        if (masked && mq == 0 && st == 1) continue;  // fully masked sub-tile
        floatx4 s = (floatx4){0.f, 0.f, 0.f, 0.f};
        s = mfma16(ka[st][0], qf[mq][0], s);
        s = mfma16(ka[st][1], qf[mq][1], s);
        f16x4 pf;
        float ps = 0.f;
        const bool diag = masked && (mq == st);
#pragma unroll
        for (int r = 0; r < 4; r++) {
          float p = exp2f(fmaf(s[r], C1, -C2));
          if (diag && (quad * 4 + r > col)) p = 0.f;
          ps += p;
          pf[r] = (f16)p;
        }
        lsum[mq] += ps;
#pragma unroll
        for (int sub = 0; sub < 4; sub++) {
          f16x4 va;
#pragma unroll
          for (int jj = 0; jj < 4; jj++) va[jj] = vv[sub][st * 4 + jj];
          o[mq][sub] = mfma_pv(va, pf, o[mq][sub]);
        }
      }
    }
  }

  if (wv != 0) {
#pragma unroll
    for (int mq = 0; mq < 2; mq++) {
#pragma unroll
      for (int sub = 0; sub < 4; sub++) mbuf[wv - 1][mq * 4 + sub][lane] = o[mq][sub];
      lbuf[wv - 1][mq][lane] = lsum[mq];
    }
  }
  __syncthreads();
  if (wv == 0) {
#pragma unroll
    for (int w = 0; w < 3; w++)
#pragma unroll
      for (int mq = 0; mq < 2; mq++) {
#pragma unroll
        for (int sub = 0; sub < 4; sub++) o[mq][sub] += mbuf[w][mq * 4 + sub][lane];
        lsum[mq] += lbuf[w][mq][lane];
      }
#pragma unroll
    for (int mq = 0; mq < 2; mq++) {
      lsum[mq] += __shfl_xor(lsum[mq], 16);
      lsum[mq] += __shfl_xor(lsum[mq], 32);
      const float rinv = 1.f / lsum[mq];
      const int qrow = qbase + mq * 16 + col;
#pragma unroll
      for (int sub = 0; sub < 4; sub++) {
        bf16x4 yv;
#pragma unroll
        for (int r = 0; r < 4; r++) yv[r] = (bf16)(o[mq][sub][r] * rinv);
        *(bf16x4*)&Y[((size_t)b * T_ + qrow) * C_ + h * 64 + sub * 16 + quad * 4] = yv;
      }
    }
  }
}

extern "C" void kernel_launch(void* const* d_in, const int* in_sizes, int n_in,
                              void* d_out, int out_size, void* d_ws, size_t ws_size,
                              hipStream_t stream) {
  (void)in_sizes; (void)n_in; (void)out_size; (void)ws_size;
  const float* x      = (const float*)d_in[0];  // [B*T, C]
  const float* w_qkv  = (const float*)d_in[1];  // [C, 3C]
  const float* b_qkv  = (const float*)d_in[2];  // [3C]
  const float* w_proj = (const float*)d_in[3];  // [C, C]
  const float* b_proj = (const float*)d_in[4];  // [C]

  char* ws = (char*)d_ws;
  bf16* wqkv_t  = (bf16*)(ws);                  // [3C, C]   6291456 B
  bf16* wproj_t = (bf16*)(ws + 6291456);        // [C, C]    2097152 B
  bf16* qb      = (bf16*)(ws + 8388608);        // [B,H,T,D] 16777216 B
  bf16* kbuf    = (bf16*)(ws + 25165824);       // K frag-major 16777216 B
  f16*  vtbuf   = (f16*)(ws + 41943040);        // V frag-major 16777216 B
  bf16* yb      = (bf16*)(ws + 58720256);       // [B*T, C]  16777216 B
  bf16* xb      = (bf16*)(ws + 58720256);       // aliases yb (dead before attn)

  // one-time opt-in for 128 KiB dynamic LDS (host-side, capture-safe)
  static bool attr_done = false;
  if (!attr_done) {
    hipFuncSetAttribute(reinterpret_cast<const void*>(gemm_qkv),
                        hipFuncAttributeMaxDynamicSharedMemorySize, 131072);
    attr_done = true;
  }

  cvt_bf16<<<8192, 256, 0, stream>>>(x, xb);
  transpose_f32<<<dim3(96, 32), 256, 0, stream>>>(w_qkv, wqkv_t, 1024, 3072);
  transpose_f32<<<dim3(32, 32), 256, 0, stream>>>(w_proj, wproj_t, 1024, 1024);
  // SWAPPED: A = wqkv_t (channels), Bt = xb (tokens)
  gemm_qkv<<<dim3(384), dim3(512), 131072, stream>>>(wqkv_t, xb, b_qkv, qb, kbuf,
                                                     vtbuf);
  attn<<<dim3(4096), 256, 0, stream>>>(qb, kbuf, vtbuf, yb);
  gemm128<1><<<dim3(8, 64), 256, 0, stream>>>(yb, wproj_t, b_proj, d_out, nullptr,
                                              nullptr, 8192, 1024, 1024);
}